// Round 8
// baseline (846.295 us; speedup 1.0000x reference)
//
#include <hip/hip_runtime.h>

#define H 128
#define D 2
#define T_OBS 20
#define BATCH 16384
#define PRED 30
#define M 16          // batch rows per block
#define NTH 512       // 8 waves; wave wv owns units 16*wv..16*wv+15, all 4 gates
#define FP 132        // padded f32 row stride for LN staging
#define LN_EPS 1e-5f
#define HBUF 2048     // bf16 elements per h plane (16 rows x 128 k, A-fragment order)

typedef __attribute__((ext_vector_type(8))) short short8_t;
typedef __attribute__((ext_vector_type(4))) float float4_t;

// A-fragment layout: h[m][k] stored at ((k>>3)*16 + m)*8 + (k&7).
// Pure permutation of R3's row-major [m][k] layout — same values, relocated
// 16-byte groups so the wave's ds_read_b128 is lane-linear (conflict-free).
#define AIDX(m,u) (((((u)>>3)*16) + (m))*8 + ((u)&7))

__device__ __forceinline__ float fast_rcp(float x){ return __builtin_amdgcn_rcpf(x); }
__device__ __forceinline__ float sig_f(float x){ return fast_rcp(1.f + __expf(-x)); }
__device__ __forceinline__ float tanh_f(float x){ return 1.f - 2.f*fast_rcp(__expf(2.f*x)+1.f); }

__device__ __forceinline__ short f2bf(float f){      // RNE float->bf16
  union{float f; unsigned u;} v; v.f = f;
  unsigned r = (v.u + 0x7FFFu + ((v.u>>16)&1u)) >> 16;
  return (short)r;
}
__device__ __forceinline__ float bf2f(short s){
  union{float f; unsigned u;} v; v.u = ((unsigned)(unsigned short)s) << 16;
  return v.f;
}

// Per-phase per-wave constants: bf16 B-fragments for 16 units x 4 gates (64 VGPRs).
struct PhaseConsts {
  short8_t bw[4][4];
  float bs[4], w0[4], w1[4];
};

__device__ __forceinline__ void load_phase(PhaseConsts& P, const float* __restrict__ Whh,
                                           const float* __restrict__ Wih,
                                           const float* __restrict__ bih,
                                           const float* __restrict__ bhh,
                                           int wv, int l15, int q){
#pragma unroll
  for(int g=0; g<4; g++){
    const int n = g*H + 16*wv + l15;
    P.bs[g] = bih[n] + bhh[n];
    P.w0[g] = Wih[n*D + 0];
    P.w1[g] = Wih[n*D + 1];
#pragma unroll
    for(int ks=0; ks<4; ks++){
      const float* p = Whh + (size_t)n*H + ks*32 + q*8;  // B[k][n]=Whh[n][k]
      float4 a = *(const float4*)p;
      float4 b = *(const float4*)(p+4);
      short8_t f;
      f[0]=f2bf(a.x); f[1]=f2bf(a.y); f[2]=f2bf(a.z); f[3]=f2bf(a.w);
      f[4]=f2bf(b.x); f[5]=f2bf(b.y); f[6]=f2bf(b.z); f[7]=f2bf(b.w);
      P.bw[g][ks] = f;
    }
  }
}

// One LSTM cell step — arithmetic identical to R3's passing kernel; only the
// LDS addresses of h changed (A-fragment permutation). hcur/hnxt are plane
// bases: hi at +0, lo at +HBUF. One barrier.
__device__ __forceinline__ void cell_step(const short* __restrict__ hcur,
                                          short* __restrict__ hnxt,
                                          const float* __restrict__ xsrc,
                                          const PhaseConsts& P, float (&c)[4],
                                          int wv, int l15, int q, int lane){
  float4_t acc[4];
  float x0[4], x1[4];
#pragma unroll
  for(int r=0; r<4; r++){
    x0[r] = xsrc[(4*q+r)*2 + 0];
    x1[r] = xsrc[(4*q+r)*2 + 1];
  }
#pragma unroll
  for(int g=0; g<4; g++)
#pragma unroll
    for(int r=0; r<4; r++)
      acc[g][r] = fmaf(P.w1[g], x1[r], fmaf(P.w0[g], x0[r], P.bs[g]));

#pragma unroll
  for(int ks=0; ks<4; ks++){
    // value at AIDX(l15, ks*32+q*8+j) == R3's hsh[cur][plane][l15][ks*32+q*8+j]
    const short8_t ahi = *(const short8_t*)&hcur[ks*512 + lane*8];
    const short8_t alo = *(const short8_t*)&hcur[HBUF + ks*512 + lane*8];
#pragma unroll
    for(int g=0; g<4; g++){
      acc[g] = __builtin_amdgcn_mfma_f32_16x16x32_bf16(ahi, P.bw[g][ks], acc[g], 0,0,0);
      acc[g] = __builtin_amdgcn_mfma_f32_16x16x32_bf16(alo, P.bw[g][ks], acc[g], 0,0,0);
    }
  }
  const int u = 16*wv + l15;
  const int segbase = (u>>3)*128 + (u&7);   // AIDX(m,u) = segbase + m*8
#pragma unroll
  for(int r=0; r<4; r++){
    const float iv = sig_f(acc[0][r]);
    const float fv = sig_f(acc[1][r]);
    const float gv = tanh_f(acc[2][r]);
    const float ov = sig_f(acc[3][r]);
    const float cc = fmaf(fv, c[r], iv*gv);
    c[r] = cc;
    const float hv = ov * tanh_f(cc);
    const short hi = f2bf(hv);
    const short lo = f2bf(hv - bf2f(hi));
    const int a = segbase + (4*q+r)*8;
    hnxt[a] = hi;
    hnxt[HBUF + a] = lo;
  }
  __syncthreads();
}

// LayerNorm over 128 units for 16 rows; threads 0..255, 16 threads/row.
// Verbatim from R3.
__device__ __forceinline__ void layernorm16(const float (*src)[FP], float (*dst)[FP],
                                            const float* __restrict__ g,
                                            const float* __restrict__ b, int tid){
  if(tid >= 256) return;
  const int m = tid >> 4, sub = tid & 15;
  float v[8];
  float s = 0.f, s2 = 0.f;
#pragma unroll
  for(int j=0;j<8;j++){ v[j] = src[m][sub*8+j]; s += v[j]; s2 = fmaf(v[j], v[j], s2); }
#pragma unroll
  for(int msk=1; msk<16; msk<<=1){ s += __shfl_xor(s, msk, 64); s2 += __shfl_xor(s2, msk, 64); }
  const float mean = s * (1.f/H);
  const float var  = s2 * (1.f/H) - mean*mean;
  const float inv  = rsqrtf(var + LN_EPS);
#pragma unroll
  for(int j=0;j<8;j++){
    const int u = sub*8+j;
    dst[m][u] = fmaf((v[j]-mean)*inv, g[u], b[u]);
  }
}

// fc = h @ Wfc^T + bfc — R3's exact thread mapping (threads 0..255, m=tid>>4,
// d=(tid>>3)&1, ch=tid&7) and exact j-summation order over u=ch*16+j; only the
// h read addresses go through AIDX.
__device__ __forceinline__ void fc_step(const short* __restrict__ hb,
                                        const float (*wfc)[H], const float* __restrict__ bfcs,
                                        float (*xb)[D], float* __restrict__ gout,
                                        int row0, int tid){
  if(tid >= 256) return;
  const int m = tid >> 4, d = (tid >> 3) & 1, ch = tid & 7;
  // u = ch*16 + j: j=0..7 in group (m, 2ch), j=8..15 in group (m, 2ch+1)
  const short8_t h0 = *(const short8_t*)&hb[((2*ch)*16 + m)*8];
  const short8_t h1 = *(const short8_t*)&hb[((2*ch+1)*16 + m)*8];
  const short8_t l0 = *(const short8_t*)&hb[HBUF + ((2*ch)*16 + m)*8];
  const short8_t l1 = *(const short8_t*)&hb[HBUF + ((2*ch+1)*16 + m)*8];
  const float* w = &wfc[d][ch*16];
  float s = 0.f;
#pragma unroll
  for(int j=0;j<8;j++)  s = fmaf(bf2f(h0[j]) + bf2f(l0[j]), w[j], s);
#pragma unroll
  for(int j=0;j<8;j++)  s = fmaf(bf2f(h1[j]) + bf2f(l1[j]), w[8+j], s);
  s += __shfl_xor(s, 1, 64); s += __shfl_xor(s, 2, 64); s += __shfl_xor(s, 4, 64);
  if(ch == 0){
    const float vv = s + bfcs[d];
    xb[m][d] = vv;
    gout[(size_t)(row0+m)*D + d] = vv;
  }
}

__global__ __launch_bounds__(NTH, 2) void traj_kernel(
    const float* __restrict__ pos, const float* __restrict__ speed,
    const float* __restrict__ Wih_pe, const float* __restrict__ Whh_pe,
    const float* __restrict__ bih_pe, const float* __restrict__ bhh_pe,
    const float* __restrict__ Wih_se, const float* __restrict__ Whh_se,
    const float* __restrict__ bih_se, const float* __restrict__ bhh_se,
    const float* __restrict__ ln_g, const float* __restrict__ ln_b,
    const float* __restrict__ Wih_sd, const float* __restrict__ Whh_sd,
    const float* __restrict__ bih_sd, const float* __restrict__ bhh_sd,
    const float* __restrict__ Wih_pd, const float* __restrict__ Whh_pd,
    const float* __restrict__ bih_pd, const float* __restrict__ bhh_pd,
    const float* __restrict__ Wfc, const float* __restrict__ bfc,
    float* __restrict__ out)
{
  __shared__ __align__(16) short hsh[2][2*HBUF];   // [buf][hi plane | lo plane]
  __shared__ float tmpf[M][FP];
  __shared__ float hpoN[M][FP];
  __shared__ float cpoN[M][FP];
  __shared__ float seqx[2][T_OBS][M][D];
  __shared__ float xbuf[M][D];
  __shared__ float wfcs[D][H];
  __shared__ float bfcs[2];

  const int tid  = threadIdx.x;
  const int lane = tid & 63;
  const int wv   = tid >> 6;
  const int q    = lane >> 4;
  const int l15  = lane & 15;
  const int row0 = blockIdx.x * M;
  const int u    = 16*wv + l15;

  // ---- stage inputs (verbatim R3) ----
  for(int idx = tid; idx < 2*T_OBS*M*D; idx += NTH){
    const int chain = idx / (T_OBS*M*D);
    const int rem   = idx % (T_OBS*M*D);
    const int t = rem >> 5, e = rem & 31;
    const float* src = chain ? speed : pos;
    seqx[chain][t][e>>1][e&1] = src[(size_t)t*BATCH*D + row0*D + e];
  }
  if(tid < D*H) wfcs[tid>>7][tid&127] = Wfc[tid];
  if(tid < 2)   bfcs[tid] = bfc[tid];
  { int* hz = (int*)&hsh[0][0];                     // zero buf0, both planes
    for(int idx = tid; idx < HBUF; idx += NTH) hz[idx] = 0; }

  PhaseConsts P;
  float c[4];
  load_phase(P, Whh_pe, Wih_pe, bih_pe, bhh_pe, wv, l15, q);
#pragma unroll
  for(int r=0;r<4;r++) c[r] = 0.f;
  __syncthreads();

  // ---------- phase 1: pos encoder ----------
  int cur = 0;
  for(int t=0; t<T_OBS; t++){
    cell_step(hsh[cur], hsh[cur^1], &seqx[0][t][0][0], P, c, wv, l15, q, lane);
    cur ^= 1;
  }
  for(int idx=tid; idx<M*H; idx+=NTH){
    const int m = idx>>7, uu = idx&127;
    const int a = AIDX(m,uu);
    tmpf[m][uu] = bf2f(hsh[cur][a]) + bf2f(hsh[cur][HBUF + a]);
  }
  __syncthreads();
  layernorm16(tmpf, hpoN, ln_g, ln_b, tid);
  __syncthreads();
#pragma unroll
  for(int r=0;r<4;r++) tmpf[4*q+r][u] = c[r];
  __syncthreads();
  layernorm16(tmpf, cpoN, ln_g, ln_b, tid);
  __syncthreads();

  // ---------- phase 2: speed encoder ----------
  load_phase(P, Whh_se, Wih_se, bih_se, bhh_se, wv, l15, q);
#pragma unroll
  for(int r=0;r<4;r++) c[r] = 0.f;
  { int* hz = (int*)&hsh[0][0];
    for(int idx = tid; idx < HBUF; idx += NTH) hz[idx] = 0; }
  cur = 0;
  __syncthreads();
  for(int t=0; t<T_OBS; t++){
    cell_step(hsh[cur], hsh[cur^1], &seqx[1][t][0][0], P, c, wv, l15, q, lane);
    cur ^= 1;
  }
  for(int idx=tid; idx<M*H; idx+=NTH){
    const int m = idx>>7, uu = idx&127;
    const int a = AIDX(m,uu);
    tmpf[m][uu] = bf2f(hsh[cur][a]) + bf2f(hsh[cur][HBUF + a]);
  }
  __syncthreads();
  layernorm16(tmpf, tmpf, ln_g, ln_b, tid);
  __syncthreads();
  // hds = LN(hsp) + LN(hpo) -> hsh[0] (bf16 hi/lo, A-layout)
  for(int idx=tid; idx<M*H; idx+=NTH){
    const int m = idx>>7, uu = idx&127;
    const float v = tmpf[m][uu] + hpoN[m][uu];
    const short hi = f2bf(v);
    const short lo = f2bf(v - bf2f(hi));
    const int a = AIDX(m,uu);
    hsh[0][a] = hi;
    hsh[0][HBUF + a] = lo;
  }
  __syncthreads();
  // cds = LN(csp) + LN(cpo)
#pragma unroll
  for(int r=0;r<4;r++) tmpf[4*q+r][u] = c[r];
  __syncthreads();
  layernorm16(tmpf, tmpf, ln_g, ln_b, tid);
  __syncthreads();
#pragma unroll
  for(int r=0;r<4;r++) c[r] = tmpf[4*q+r][u] + cpoN[4*q+r][u];
  if(tid < M*D) xbuf[tid>>1][tid&1] = seqx[1][T_OBS-1][tid>>1][tid&1];   // curr_speed
  load_phase(P, Whh_sd, Wih_sd, bih_sd, bhh_sd, wv, l15, q);
  __syncthreads();

  // ---------- phase 3: speed decoder (unfused, fp32 fc feedback — R3 path) ----------
  float* spd_out = out + (size_t)PRED*BATCH*D;
  cur = 0;
  for(int t=0; t<PRED; t++){
    cell_step(hsh[cur], hsh[cur^1], &xbuf[0][0], P, c, wv, l15, q, lane);
    fc_step(hsh[cur^1], wfcs, bfcs, xbuf, spd_out + (size_t)t*BATCH*D, row0, tid);
    __syncthreads();
    cur ^= 1;
  }

  // ---------- phase 4: pos decoder ----------
  for(int idx=tid; idx<M*H; idx+=NTH){
    const int m = idx>>7, uu = idx&127;
    const float v = hpoN[m][uu];
    const short hi = f2bf(v);
    const short lo = f2bf(v - bf2f(hi));
    const int a = AIDX(m,uu);
    hsh[0][a] = hi;
    hsh[0][HBUF + a] = lo;
  }
#pragma unroll
  for(int r=0;r<4;r++) c[r] = cpoN[4*q+r][u];
  if(tid < M*D) xbuf[tid>>1][tid&1] = seqx[0][T_OBS-1][tid>>1][tid&1];   // curr_pos
  load_phase(P, Whh_pd, Wih_pd, bih_pd, bhh_pd, wv, l15, q);
  __syncthreads();
  cur = 0;
  for(int t=0; t<PRED; t++){
    cell_step(hsh[cur], hsh[cur^1], &xbuf[0][0], P, c, wv, l15, q, lane);
    fc_step(hsh[cur^1], wfcs, bfcs, xbuf, out + (size_t)t*BATCH*D, row0, tid);
    __syncthreads();
    cur ^= 1;
  }
}

extern "C" void kernel_launch(void* const* d_in, const int* in_sizes, int n_in,
                              void* d_out, int out_size, void* d_ws, size_t ws_size,
                              hipStream_t stream)
{
  const float* pos    = (const float*)d_in[0];
  const float* speed  = (const float*)d_in[1];
  const float* Wih_pe = (const float*)d_in[2];
  const float* Whh_pe = (const float*)d_in[3];
  const float* bih_pe = (const float*)d_in[4];
  const float* bhh_pe = (const float*)d_in[5];
  const float* Wih_se = (const float*)d_in[6];
  const float* Whh_se = (const float*)d_in[7];
  const float* bih_se = (const float*)d_in[8];
  const float* bhh_se = (const float*)d_in[9];
  const float* ln_g   = (const float*)d_in[10];
  const float* ln_b   = (const float*)d_in[11];
  const float* Wih_sd = (const float*)d_in[12];
  const float* Whh_sd = (const float*)d_in[13];
  const float* bih_sd = (const float*)d_in[14];
  const float* bhh_sd = (const float*)d_in[15];
  const float* Wih_pd = (const float*)d_in[16];
  const float* Whh_pd = (const float*)d_in[17];
  const float* bih_pd = (const float*)d_in[18];
  const float* bhh_pd = (const float*)d_in[19];
  const float* Wfc    = (const float*)d_in[20];
  const float* bfc    = (const float*)d_in[21];

  traj_kernel<<<BATCH/M, NTH, 0, stream>>>(
      pos, speed, Wih_pe, Whh_pe, bih_pe, bhh_pe,
      Wih_se, Whh_se, bih_se, bhh_se, ln_g, ln_b,
      Wih_sd, Whh_sd, bih_sd, bhh_sd, Wih_pd, Whh_pd, bih_pd, bhh_pd,
      Wfc, bfc, (float*)d_out);
}